// Round 1
// baseline (238.642 us; speedup 1.0000x reference)
//
#include <hip/hip_runtime.h>
#include <hip/hip_bf16.h>

// out[n] = sum_m exp(-GAMMA * max(||x_n||^2 + ||y_m||^2 - 2 x.y, 0)) * W[m] + b
// n=16384, m=8192, d=512. Strategy: bf16 MFMA for the cross-term GEMM
// (137.4 GFLOP, compute-bound), exact f32 norms, fused exp+weighted-rowsum
// epilogue with atomicAdd.
//
// Workspace layout (needs ~25.3 MB):
//   Xb  bf16[16384*512]  @ 0          (16.78 MB)
//   Yb  bf16[ 8192*512]  @ 16777216   ( 8.39 MB)
//   x2  f32 [16384]      @ 25165824   (64 KB)
//   y2  f32 [ 8192]      @ 25231360   (32 KB)

#define GAMMA 0.002f

typedef __bf16 bf16x8 __attribute__((ext_vector_type(8)));
typedef float  f32x4  __attribute__((ext_vector_type(4)));
typedef __attribute__((address_space(3))) void lds_void_t;
typedef __attribute__((address_space(1))) const void gl_void_t;

// ---------------- prep: f32 -> bf16 + row squared-norm (one wave per row, d=512)
__global__ __launch_bounds__(256) void prep_kernel(const float* __restrict__ src,
                                                   __bf16* __restrict__ dst,
                                                   float* __restrict__ norms,
                                                   int nrows) {
    const int wid  = threadIdx.x >> 6;
    const int lane = threadIdx.x & 63;
    const int row  = blockIdx.x * 4 + wid;
    if (row >= nrows) return;
    const float4* s = reinterpret_cast<const float4*>(src + (size_t)row * 512);
    float4 v0 = s[lane * 2];
    float4 v1 = s[lane * 2 + 1];
    float acc = v0.x * v0.x + v0.y * v0.y + v0.z * v0.z + v0.w * v0.w
              + v1.x * v1.x + v1.y * v1.y + v1.z * v1.z + v1.w * v1.w;
    bf16x8 o;
    o[0] = (__bf16)v0.x; o[1] = (__bf16)v0.y; o[2] = (__bf16)v0.z; o[3] = (__bf16)v0.w;
    o[4] = (__bf16)v1.x; o[5] = (__bf16)v1.y; o[6] = (__bf16)v1.z; o[7] = (__bf16)v1.w;
    *reinterpret_cast<bf16x8*>(dst + (size_t)row * 512 + lane * 8) = o;
#pragma unroll
    for (int off = 32; off >= 1; off >>= 1) acc += __shfl_xor(acc, off, 64);
    if (lane == 0) norms[row] = acc;
}

// ---------------- init out[n] = b
__global__ void init_out(float* __restrict__ out, const float* __restrict__ b, int n) {
    int i = blockIdx.x * blockDim.x + threadIdx.x;
    if (i < n) out[i] = b[0];
}

// ---------------- fused RBF GEMM: 128x128 tile, 4 waves (2x2), 16x16x32 bf16 MFMA
// grid: (16384/128) * (8192/128) = 128 * 64 = 8192 blocks
__global__ __launch_bounds__(256, 2) void rbf_gemm(
    const __bf16* __restrict__ Xb, const __bf16* __restrict__ Yb,
    const float* __restrict__ x2, const float* __restrict__ y2,
    const float* __restrict__ W, float* __restrict__ out) {
    __shared__ __align__(16) __bf16 lA[128 * 32];
    __shared__ __align__(16) __bf16 lB[128 * 32];

    const int tid    = threadIdx.x;
    const int wid    = tid >> 6;
    const int lane   = tid & 63;
    const int tile_n = blockIdx.x >> 6;   // 0..127
    const int tile_m = blockIdx.x & 63;   // 0..63
    const int wn = wid >> 1, wm = wid & 1;

    // staging: wave wid covers LDS segments {wid*2, wid*2+1} (1 KB each = 16 rows)
    // lane -> row_in_seg = lane>>2, k-chunk = (lane&3)*8 bf16 (16 B)
    const int seg0   = wid * 2;
    const int seg1   = wid * 2 + 1;
    const int rseg   = lane >> 2;
    const int kc     = (lane & 3) * 8;
    const size_t a_off0 = ((size_t)(tile_n * 128 + seg0 * 16 + rseg)) * 512 + kc;
    const size_t a_off1 = ((size_t)(tile_n * 128 + seg1 * 16 + rseg)) * 512 + kc;
    const size_t b_off0 = ((size_t)(tile_m * 128 + seg0 * 16 + rseg)) * 512 + kc;
    const size_t b_off1 = ((size_t)(tile_m * 128 + seg1 * 16 + rseg)) * 512 + kc;

    f32x4 acc[4][4] = {};

    const int fr = lane & 15;          // fragment row (both A and B^T pattern)
    const int kq = (lane >> 4) * 8;    // fragment k offset (bf16 elems)

    for (int kk = 0; kk < 16; ++kk) {
        const int k0 = kk * 32;
        __syncthreads();
        __builtin_amdgcn_global_load_lds((gl_void_t*)(Xb + a_off0 + k0),
                                         (lds_void_t*)(lA + seg0 * 512), 16, 0, 0);
        __builtin_amdgcn_global_load_lds((gl_void_t*)(Xb + a_off1 + k0),
                                         (lds_void_t*)(lA + seg1 * 512), 16, 0, 0);
        __builtin_amdgcn_global_load_lds((gl_void_t*)(Yb + b_off0 + k0),
                                         (lds_void_t*)(lB + seg0 * 512), 16, 0, 0);
        __builtin_amdgcn_global_load_lds((gl_void_t*)(Yb + b_off1 + k0),
                                         (lds_void_t*)(lB + seg1 * 512), 16, 0, 0);
        __syncthreads();

        bf16x8 af[4], bg[4];
#pragma unroll
        for (int ai = 0; ai < 4; ++ai)
            af[ai] = *reinterpret_cast<const bf16x8*>(&lA[(wn * 64 + ai * 16 + fr) * 32 + kq]);
#pragma unroll
        for (int bj = 0; bj < 4; ++bj)
            bg[bj] = *reinterpret_cast<const bf16x8*>(&lB[(wm * 64 + bj * 16 + fr) * 32 + kq]);
#pragma unroll
        for (int ai = 0; ai < 4; ++ai)
#pragma unroll
            for (int bj = 0; bj < 4; ++bj)
                acc[ai][bj] = __builtin_amdgcn_mfma_f32_16x16x32_bf16(
                    af[ai], bg[bj], acc[ai][bj], 0, 0, 0);
    }

    // ---------------- epilogue: exp + weighted row-sum
    // C/D layout (16x16x32): col = lane&15 (m), row = (lane>>4)*4 + reg (n)
    const int lrow = lane >> 4, lcol = lane & 15;
    float y2v[4], wv[4];
#pragma unroll
    for (int bj = 0; bj < 4; ++bj) {
        int m = tile_m * 128 + wm * 64 + bj * 16 + lcol;
        y2v[bj] = y2[m];
        wv[bj]  = W[m];
    }
#pragma unroll
    for (int ai = 0; ai < 4; ++ai) {
#pragma unroll
        for (int i = 0; i < 4; ++i) {
            const int n  = tile_n * 128 + wn * 64 + ai * 16 + lrow * 4 + i;
            const float x2n = x2[n];
            float s = 0.f;
#pragma unroll
            for (int bj = 0; bj < 4; ++bj) {
                float d2 = x2n + y2v[bj] - 2.0f * acc[ai][bj][i];
                d2 = fmaxf(d2, 0.f);
                s += __expf(-GAMMA * d2) * wv[bj];
            }
            // reduce across the 16 lanes sharing this n (xor bits 0..3)
#pragma unroll
            for (int off = 1; off < 16; off <<= 1) s += __shfl_xor(s, off, 64);
            if (lcol == 0) atomicAdd(&out[n], s);
        }
    }
}

extern "C" void kernel_launch(void* const* d_in, const int* in_sizes, int n_in,
                              void* d_out, int out_size, void* d_ws, size_t ws_size,
                              hipStream_t stream) {
    const float* X = (const float*)d_in[0];   // 16384 x 512
    const float* Y = (const float*)d_in[1];   //  8192 x 512
    const float* W = (const float*)d_in[2];   // 8192
    const float* b = (const float*)d_in[3];   // 1
    float* out = (float*)d_out;               // 16384

    char* ws = (char*)d_ws;
    __bf16* Xb = (__bf16*)(ws);
    __bf16* Yb = (__bf16*)(ws + 16777216);
    float*  x2 = (float*)(ws + 16777216 + 8388608);
    float*  y2 = (float*)(ws + 16777216 + 8388608 + 65536);

    prep_kernel<<<4096, 256, 0, stream>>>(X, Xb, x2, 16384);
    prep_kernel<<<2048, 256, 0, stream>>>(Y, Yb, y2, 8192);
    init_out<<<64, 256, 0, stream>>>(out, b, 16384);
    rbf_gemm<<<8192, 256, 0, stream>>>(Xb, Yb, x2, y2, W, out);
}